// Round 5
// baseline (174.094 us; speedup 1.0000x reference)
//
#include <hip/hip_runtime.h>
#include <hip/hip_bf16.h>

// Problem: features_1 [1,20000,256] f32, features_2 [1,8192,256] f32, map21 [8192] int
#define PP       8192
#define DIM      256
#define DIMP     272               // 256 + 16 pad dims (norm embedding in 4 of them)
#define NKF      17                // K fragments of 16
#define GS       (32 * DIMP)       // 8704 bf16 elems per 32-row group (17 frag-blocks x 512)
#define NCHUNK   16                // column chunks (grid.y); chunk = 576 cols
#define TCOLS    18                // 32-col tiles per chunk (even: 2-unrolled loop)
#define KGROUPS  288               // 256 real col-groups + 32 dummy (pad to 9216 cols)
#define KGALLOC  289               // +1 slack group (prefetch overrun target, never consumed)
#define ROWBLK   256               // rows per main block (4 waves x 64)
#define NROWBLK  (PP / ROWBLK)     // 32

typedef __bf16 bf16_t;
using bf16x8 = __attribute__((ext_vector_type(8))) __bf16;
using bf16x4 = __attribute__((ext_vector_type(4))) __bf16;
using f32x4  = __attribute__((ext_vector_type(4))) float;
using f32x16 = __attribute__((ext_vector_type(16))) float;

#define C2    20.609929155556618          // 1/(T*ln2): -dist -> log2-domain logit
#define MEXP  (-340.0f)                   // fixed log2 shift (validated rounds 3-4)
#define COEF  ((float)(-(C2 * 1.4142135623730951) * 8388608.0))  // -C2*sqrt(2)*2^23
#define KBIAS ((float)((127.0 + 340.0) * 8388608.0))             // (127 - MEXP)*2^23
#define LN2   0.6931471805599453f

// ---------------------------------------------------------------------------
// Kernel 1: gather + bf16 convert into frag-major layout + norm-embedding pad
// dims + exact fp32 diagonal logit + dummy-column init + zero-init of
// part_l / cnt / out.  One wave per row p; lane covers k = lane*4 .. +3.
// Frag-major: elem (p,k) -> G=p>>5, l31=p&31, kk=k>>4, h=(k>>3)&1, j=k&7 at
//   bf16 index G*GS + (kk*64 + h*32 + l31)*8 + j
// ---------------------------------------------------------------------------
__global__ __launch_bounds__(256) void nce_prep(
    const float* __restrict__ f1, const float* __restrict__ f2,
    const int* __restrict__ map,
    bf16_t* __restrict__ qb2, bf16_t* __restrict__ kb2,
    float* __restrict__ diag2, float* __restrict__ part_l,
    unsigned* __restrict__ cnt, float* __restrict__ out)
{
    const int tid  = threadIdx.x;
    const int wave = tid >> 6, lane = tid & 63;
    const int p    = blockIdx.x * 4 + wave;
    const int gtid = blockIdx.x * 256 + tid;

    if (gtid < PP) part_l[gtid] = 0.0f;
    if (gtid < NROWBLK) cnt[gtid] = 0u;
    if (gtid == 0) out[0] = 0.0f;

    // Dummy columns (groups 256..287): all-zero except one element per column
    // at (kk=16,h=0,j=2) = -1e5, so acc = q'.k'_dummy = -1e5 for every real row
    // (q' has 1.0 at that dim) -> exp term clamps to 0. 32 groups x 1088 chunks.
    if (gtid < 32 * (GS / 8)) {
        const int grp = 256 + gtid / (GS / 8);
        const int c   = gtid % (GS / 8);
        bf16x8 v;
        #pragma unroll
        for (int i = 0; i < 8; ++i) v[i] = (bf16_t)0.0f;
        if (c >= 1024 && c < 1056) v[2] = (bf16_t)(-1.0e5f);
        *(bf16x8*)(kb2 + (size_t)grp * GS + (size_t)c * 8) = v;
    }

    const int idx = map[p];
    const f32x4 qv = *(const f32x4*)(f1 + (size_t)idx * DIM + lane * 4);
    const f32x4 kv = *(const f32x4*)(f2 + (size_t)p * DIM + lane * 4);

    float qs = qv[0]*qv[0] + qv[1]*qv[1] + qv[2]*qv[2] + qv[3]*qv[3];
    float ks = kv[0]*kv[0] + kv[1]*kv[1] + kv[2]*kv[2] + kv[3]*kv[3];
    const f32x4 dv = qv - kv;
    float ds = dv[0]*dv[0] + dv[1]*dv[1] + dv[2]*dv[2] + dv[3]*dv[3];

    bf16x4 qo, ko;
    #pragma unroll
    for (int i = 0; i < 4; ++i) { qo[i] = (bf16_t)qv[i]; ko[i] = (bf16_t)kv[i]; }

    const int G = p >> 5, l31 = p & 31;
    const int kk = lane >> 2, h = (lane >> 1) & 1, j0 = (lane & 1) * 4;
    const size_t base = (size_t)G * GS;
    const size_t off  = base + (size_t)(kk * 64 + h * 32 + l31) * 8 + j0;
    *(bf16x4*)(qb2 + off) = qo;
    *(bf16x4*)(kb2 + off) = ko;

    #pragma unroll
    for (int s = 32; s > 0; s >>= 1) {
        qs += __shfl_xor(qs, s);
        ks += __shfl_xor(ks, s);
        ds += __shfl_xor(ds, s);
    }

    // Pad frag kk=16 (dims 256..271): q' = [qhi,qlo,1,1,0..], k' = [1,1,khi,klo,0..]
    // so extra-dim dot = -(qs+ks)/2 with bf16 hi/lo split.
    if (lane < 4) {
        const int hh = lane & 1;
        bf16x8 v;
        #pragma unroll
        for (int i = 0; i < 8; ++i) v[i] = (bf16_t)0.0f;
        if (lane == 0) {                   // q' pad, h=0 block
            const float qh = -0.5f * qs;
            const bf16_t q1 = (bf16_t)qh;
            v[0] = q1; v[1] = (bf16_t)(qh - (float)q1);
            v[2] = (bf16_t)1.0f; v[3] = (bf16_t)1.0f;
        } else if (lane == 2) {            // k' pad, h=0 block
            const float kh = -0.5f * ks;
            const bf16_t k1 = (bf16_t)kh;
            v[0] = (bf16_t)1.0f; v[1] = (bf16_t)1.0f;
            v[2] = k1; v[3] = (bf16_t)(kh - (float)k1);
        }
        bf16_t* dstp = (lane < 2) ? qb2 : kb2;
        *(bf16x8*)(dstp + base + (size_t)(1024 + hh * 32 + l31) * 8) = v;
    }
    if (lane == 0)
        diag2[p] = (float)(-C2) * __builtin_amdgcn_sqrtf(ds);  // exact diag, log2
}

// ---------------------------------------------------------------------------
// Epilogue: acc = -dist^2/2 -> l += 2^(lg - MEXP) via fixed-shift bitcast:
//   u = (u32)max(sqrt(-acc)*COEF + KBIAS, 0)
// ---------------------------------------------------------------------------
__device__ __forceinline__ void epi(const f32x16& acc0, const f32x16& acc1,
                                    float* l0, float* l1)
{
    #pragma unroll
    for (int i = 0; i < 16; ++i) {
        const float t0 = __builtin_amdgcn_sqrtf(-acc0[i]);
        const float u0 = fmaxf(fmaf(t0, COEF, KBIAS), 0.0f);
        l0[i] += __uint_as_float((unsigned)u0);
        const float t1 = __builtin_amdgcn_sqrtf(-acc1[i]);
        const float u1 = fmaxf(fmaf(t1, COEF, KBIAS), 0.0f);
        l1[i] += __uint_as_float((unsigned)u1);
    }
}

// ---------------------------------------------------------------------------
// One 32-col tile for 2 row-groups: 16 main frags through the 8-slot register
// ring (prefetching 8 frags ahead -> fine-grained vmcnt, no barriers), then
// the pad frag (pc, prefetched one tile ahead by the caller). Bumps tb.
// Prefetch offset from tile base: kk<8 -> frag kk+8 (same tile), kk>=8 ->
// next tile's frag kk-8 at (17 + kk-8) = kk+9. Last tile overruns into the
// slack group (allocated, never consumed).
// ---------------------------------------------------------------------------
__device__ __forceinline__ void tile_body(const bf16_t*& tb,
                                          const bf16x8* a0, const bf16x8* a1,
                                          bf16x8* br, const bf16x8 pc,
                                          float* l0, float* l1)
{
    f32x16 acc0 = {0,0,0,0,0,0,0,0,0,0,0,0,0,0,0,0};
    f32x16 acc1 = {0,0,0,0,0,0,0,0,0,0,0,0,0,0,0,0};
    #pragma unroll
    for (int kk = 0; kk < 16; ++kk) {
        const bf16x8 b = br[kk & 7];
        acc0 = __builtin_amdgcn_mfma_f32_32x32x16_bf16(a0[kk], b, acc0, 0, 0, 0);
        acc1 = __builtin_amdgcn_mfma_f32_32x32x16_bf16(a1[kk], b, acc1, 0, 0, 0);
        br[kk & 7] = *(const bf16x8*)(tb + ((kk < 8) ? (kk + 8) : (kk + 9)) * 512);
    }
    acc0 = __builtin_amdgcn_mfma_f32_32x32x16_bf16(a0[16], pc, acc0, 0, 0, 0);
    acc1 = __builtin_amdgcn_mfma_f32_32x32x16_bf16(a1[16], pc, acc1, 0, 0, 0);
    epi(acc0, acc1, l0, l1);
    tb += 17 * 512;
}

// ---------------------------------------------------------------------------
// Kernel 2: fused QK' GEMM + fixed-shift exp2 accumulation, BARRIER-FREE.
// Wave = 64 rows (2 groups) x 32 cols; block = 4 waves = 256 rows, all 4
// waves stream the SAME column tiles (L1 temporal sharing) independently.
// Grid 32 x 16 = 512 blocks = 2/CU = 2 waves/SIMD; regs ~250 -> lb(256,2).
// ---------------------------------------------------------------------------
__global__ __launch_bounds__(256, 2) void nce_main(
    const bf16_t* __restrict__ qb2, const bf16_t* __restrict__ kb2,
    const float* __restrict__ diag2, float* __restrict__ part_l,
    unsigned* __restrict__ cnt, float* __restrict__ out)
{
    const int tid  = threadIdx.x, wave = tid >> 6, lane = tid & 63;
    const int l31  = lane & 31, h = lane >> 5;
    const int rb   = blockIdx.x;               // row-block 0..31 (256 rows)
    const int G0   = rb * 8 + wave * 2;        // wave's first 32-row group
    const int c0g  = blockIdx.y * TCOLS;       // first col-group of chunk

    __shared__ int   s_last;
    __shared__ float red[4];

    // A fragments for 2 row groups: 2 x 17 x 4 = 136 VGPRs, 1KB/instr coalesced
    bf16x8 a0[NKF], a1[NKF];
    {
        const bf16_t* ap0 = qb2 + (size_t)G0 * GS + lane * 8;
        const bf16_t* ap1 = ap0 + GS;
        #pragma unroll
        for (int kk = 0; kk < NKF; ++kk) {
            a0[kk] = *(const bf16x8*)(ap0 + kk * 512);
            a1[kk] = *(const bf16x8*)(ap1 + kk * 512);
        }
    }

    float l0[16], l1[16];
    #pragma unroll
    for (int i = 0; i < 16; ++i) { l0[i] = 0.0f; l1[i] = 0.0f; }

    // B stream: chunk's 18 tiles are contiguous groups; frag f of tile t at
    // tb + (t*17 + f)*512 with per-lane base lane*8 (16 B contiguous / lane).
    const bf16_t* tb = kb2 + (size_t)c0g * GS + lane * 8;
    bf16x8 br[8];
    #pragma unroll
    for (int i = 0; i < 8; ++i) br[i] = *(const bf16x8*)(tb + i * 512);
    bf16x8 pcA = *(const bf16x8*)(tb + 16 * 512);   // pad frag, tile 0

    for (int tt = 0; tt < TCOLS; tt += 2) {
        const bf16x8 pcB = *(const bf16x8*)(tb + 33 * 512);   // pad, tile tt+1
        tile_body(tb, a0, a1, br, pcA, l0, l1);
        pcA = *(const bf16x8*)(tb + 33 * 512);                // pad, tile tt+2 (or slack)
        tile_body(tb, a0, a1, br, pcB, l0, l1);
    }

    // sum l across the 32 column-lanes (plain adds — fixed shift)
    #pragma unroll
    for (int s = 1; s < 32; s <<= 1) {
        #pragma unroll
        for (int i = 0; i < 16; ++i) {
            l0[i] += __shfl_xor(l0[i], s);
            l1[i] += __shfl_xor(l1[i], s);
        }
    }

    if (l31 == 0) {
        #pragma unroll
        for (int i = 0; i < 16; ++i) {
            const int r = (i & 3) + 8 * (i >> 2) + 4 * h;
            atomicAdd(&part_l[G0 * 32 + r], l0[i]);
            atomicAdd(&part_l[(G0 + 1) * 32 + r], l1[i]);
        }
    }

    __syncthreads();
    if (tid == 0) {
        __threadfence();
        s_last = (atomicAdd(&cnt[rb], 1u) == NCHUNK - 1) ? 1 : 0;
    }
    __syncthreads();
    if (s_last) {
        // all 16 chunk-blocks of this row-block done: finalize 256 rows
        const int row = rb * ROWBLK + tid;
        const float lf = atomicAdd(&part_l[row], 0.0f);        // coherent read
        float v = MEXP + __builtin_amdgcn_logf(lf) - diag2[row]; // log2 domain
        #pragma unroll
        for (int s = 1; s < 64; s <<= 1) v += __shfl_xor(v, s);
        if (lane == 0) red[wave] = v;
        __syncthreads();
        if (tid == 0)
            atomicAdd(out, (red[0] + red[1] + red[2] + red[3]) * (LN2 / (float)PP));
    }
}

// ---------------------------------------------------------------------------
extern "C" void kernel_launch(void* const* d_in, const int* in_sizes, int n_in,
                              void* d_out, int out_size, void* d_ws, size_t ws_size,
                              hipStream_t stream)
{
    const float* f1  = (const float*)d_in[0];   // [20000,256] f32
    const float* f2  = (const float*)d_in[1];   // [8192,256] f32
    const int*   map = (const int*)d_in[2];     // [8192] int
    float* out = (float*)d_out;

    // workspace layout (~9.55 MB)
    char* ws = (char*)d_ws;
    bf16_t*   qb2    = (bf16_t*)ws;                           // 256*GS*2 B
    bf16_t*   kb2    = qb2 + (size_t)256 * GS;                // 289*GS*2 B (1 slack)
    float*    diag2  = (float*)(ws + ((size_t)256 + KGALLOC) * GS * sizeof(bf16_t));
    float*    part_l = diag2 + PP;
    unsigned* cnt    = (unsigned*)(part_l + PP);

    nce_prep<<<PP / 4, 256, 0, stream>>>(f1, f2, map, qb2, kb2, diag2,
                                         part_l, cnt, out);
    nce_main<<<dim3(NROWBLK, NCHUNK), 256, 0, stream>>>(qb2, kb2, diag2,
                                                        part_l, cnt, out);
}

// Round 7
// 133.688 us; speedup vs baseline: 1.3022x; 1.3022x over previous
//
#include <hip/hip_runtime.h>
#include <hip/hip_bf16.h>

// Problem: features_1 [1,20000,256] f32, features_2 [1,8192,256] f32, map21 [8192] int
#define PP       8192
#define DIM      256
#define GS16     4096              // bf16 elems per 16-row frag-major group (8 frags x 512)
#define NCHUNK   16                // column chunks (grid.y); chunk = 512 cols
#define TCOLS    32                // 16-col tiles per chunk
#define ROWBLK   256               // rows per main block (4 waves x 64)
#define NROWBLK  (PP / ROWBLK)     // 32

typedef __bf16 bf16_t;
using bf16x8 = __attribute__((ext_vector_type(8))) __bf16;
using bf16x4 = __attribute__((ext_vector_type(4))) __bf16;
using f32x4  = __attribute__((ext_vector_type(4))) float;

#define C2    20.609929155556618          // 1/(T*ln2): -dist -> log2-domain logit
#define MEXP  (-340.0f)                   // fixed log2 shift (validated rounds 3-5)
// ROUND-6 BUG FIX: t0 = dist (full dist^2 formulation), so the exponent
// coefficient is -C2*2^23, NOT -C2*sqrt(2)*2^23 (that was for t = dist/sqrt2).
#define COEF  ((float)(-C2 * 8388608.0))                         // -C2 * 2^23
#define KBIAS ((float)((127.0 + 340.0) * 8388608.0))             // (127 - MEXP)*2^23
#define LN2   0.6931471805599453f

// ---------------------------------------------------------------------------
// Frag-major layout for a 16-row group G of a [*,256] bf16 matrix (16x16x32
// MFMA operand order): elem (p,k) -> G=p>>4, l15=p&15, frag kk=k>>5,
// lane = l15 + 16*((k>>3)&3), j = k&7; bf16 index = G*GS16 + kk*512 + lane*8 + j.
// A wave reading "ptr + lane*8 + kk*512" gets op[m=lane&15][k=kk*32+(lane>>4)*8+j]
// -- the validated (round 1) A/B operand mapping, 16 B contiguous per lane.
// ---------------------------------------------------------------------------

// ---------------------------------------------------------------------------
// Kernel 1: gather + bf16 convert into frag-major layout + fp32 norms +
// exact fp32 diagonal logit + zero-init of part_l / cnt / out.
// One wave per row p; lane covers k = lane*4 .. +3.
// ---------------------------------------------------------------------------
__global__ __launch_bounds__(256) void nce_prep(
    const float* __restrict__ f1, const float* __restrict__ f2,
    const int* __restrict__ map,
    bf16_t* __restrict__ qb2, bf16_t* __restrict__ kb2,
    float* __restrict__ qsq, float* __restrict__ ksq,
    float* __restrict__ diag2, float* __restrict__ part_l,
    unsigned* __restrict__ cnt, float* __restrict__ out)
{
    const int tid  = threadIdx.x;
    const int wave = tid >> 6, lane = tid & 63;
    const int p    = blockIdx.x * 4 + wave;
    const int gtid = blockIdx.x * 256 + tid;

    if (gtid < PP) part_l[gtid] = 0.0f;
    if (gtid < NROWBLK) cnt[gtid] = 0u;
    if (gtid == 0) out[0] = 0.0f;

    const int idx = map[p];
    const f32x4 qv = *(const f32x4*)(f1 + (size_t)idx * DIM + lane * 4);
    const f32x4 kv = *(const f32x4*)(f2 + (size_t)p * DIM + lane * 4);

    float qs = qv[0]*qv[0] + qv[1]*qv[1] + qv[2]*qv[2] + qv[3]*qv[3];
    float ks = kv[0]*kv[0] + kv[1]*kv[1] + kv[2]*kv[2] + kv[3]*kv[3];
    const f32x4 dv = qv - kv;
    float ds = dv[0]*dv[0] + dv[1]*dv[1] + dv[2]*dv[2] + dv[3]*dv[3];

    bf16x4 qo, ko;
    #pragma unroll
    for (int i = 0; i < 4; ++i) { qo[i] = (bf16_t)qv[i]; ko[i] = (bf16_t)kv[i]; }

    // frag-major write position for k = lane*4 .. +3
    const int G = p >> 4, l15 = p & 15;
    const size_t off = (size_t)G * GS16 + (size_t)(lane >> 3) * 512
                     + (size_t)(l15 + 16 * ((lane >> 1) & 3)) * 8 + (lane & 1) * 4;
    *(bf16x4*)(qb2 + off) = qo;
    *(bf16x4*)(kb2 + off) = ko;

    #pragma unroll
    for (int s = 32; s > 0; s >>= 1) {
        qs += __shfl_xor(qs, s);
        ks += __shfl_xor(ks, s);
        ds += __shfl_xor(ds, s);
    }
    if (lane == 0) {
        qsq[p]   = qs;
        ksq[p]   = ks;
        diag2[p] = (float)(-C2) * __builtin_amdgcn_sqrtf(ds);  // exact diag, log2
    }
}

// ---------------------------------------------------------------------------
// Kernel 2: fused QK^T (16x16x32 MFMA) + dist + fixed-shift exp2 accumulation.
// BARRIER-FREE K-loop: B frags stream global->VGPR through a 4-slot register
// ring (fine-grained vmcnt, no __syncthreads in the hot loop).
// Wave = 64 rows (4 row-groups) x 16 cols/tile; block = 4 waves = 256 rows,
// all 4 waves stream the SAME column chunk (L1 temporal sharing).
// Live set ~210 regs: A 128 + ring 16 + acc 16 + l 16 + qs 16 + temps.
// Grid 32 x 16 = 512 blocks = 2/CU = 2 waves/SIMD.
// ---------------------------------------------------------------------------
__global__ __launch_bounds__(256, 2) void nce_main(
    const bf16_t* __restrict__ qb2, const bf16_t* __restrict__ kb2,
    const float* __restrict__ qsq, const float* __restrict__ ksq,
    const float* __restrict__ diag2, float* __restrict__ part_l,
    unsigned* __restrict__ cnt, float* __restrict__ out)
{
    const int tid  = threadIdx.x, wave = tid >> 6, lane = tid & 63;
    const int quad = lane >> 4, l15 = lane & 15;
    const int rb   = blockIdx.x;               // row-block 0..31 (256 rows)
    const int ch   = blockIdx.y;               // column chunk 0..15 (512 cols)
    const int Gb   = rb * 16 + wave * 4;       // wave's first 16-row group
    const int rbase = rb * ROWBLK + wave * 64; // wave's first row

    __shared__ int   s_last;
    __shared__ float red[4];

    // A fragments, 4 row-groups x 8 K-frags = 128 VGPRs, 1KB/instr coalesced
    bf16x8 a[4][8];
    {
        const bf16_t* ap = qb2 + (size_t)Gb * GS16 + lane * 8;
        #pragma unroll
        for (int rg = 0; rg < 4; ++rg)
            #pragma unroll
            for (int f = 0; f < 8; ++f)
                a[rg][f] = *(const bf16x8*)(ap + rg * GS16 + f * 512);
    }

    // qs for this lane's 16 acc rows: i=(rg*4+r) -> row = rg*16 + quad*4 + r
    float qs[16];
    #pragma unroll
    for (int i = 0; i < 16; ++i)
        qs[i] = qsq[rbase + (i >> 2) * 16 + quad * 4 + (i & 3)];

    float l[16];
    #pragma unroll
    for (int i = 0; i < 16; ++i) l[i] = 0.0f;

    // B stream: chunk = 32 contiguous 16-col groups; frag f of tile t at
    // tb + (t*8 + f)*512. 4-slot ring, prefetch distance 4 frags (~272 cyc).
    const bf16_t* tb = kb2 + (size_t)ch * 32 * GS16 + lane * 8;
    bf16x8 br[4];
    #pragma unroll
    for (int s = 0; s < 4; ++s) br[s] = *(const bf16x8*)(tb + s * 512);
    const float* kqp = ksq + ch * 512 + l15;

    for (int t = 0; t < TCOLS; ++t) {
        const float kq = kqp[t * 16];          // this lane's column norm
        f32x4 acc0 = {0,0,0,0}, acc1 = {0,0,0,0}, acc2 = {0,0,0,0}, acc3 = {0,0,0,0};
        #pragma unroll
        for (int f = 0; f < 8; ++f) {
            const bf16x8 b = br[f & 3];
            acc0 = __builtin_amdgcn_mfma_f32_16x16x32_bf16(a[0][f], b, acc0, 0, 0, 0);
            acc1 = __builtin_amdgcn_mfma_f32_16x16x32_bf16(a[1][f], b, acc1, 0, 0, 0);
            acc2 = __builtin_amdgcn_mfma_f32_16x16x32_bf16(a[2][f], b, acc2, 0, 0, 0);
            acc3 = __builtin_amdgcn_mfma_f32_16x16x32_bf16(a[3][f], b, acc3, 0, 0, 0);
            // refill: frag f+4 of the global frag stream (overruns 4 frags
            // past the last tile -> 8 KB slack after kb2, never consumed)
            br[f & 3] = *(const bf16x8*)(tb + (size_t)(t * 8 + f + 4) * 512);
        }

        // dist^2 = qs + kq - 2*acc;  l += 2^(-C2*dist - MEXP) via bitcast
        #pragma unroll
        for (int i = 0; i < 16; ++i) {
            const float av = (i < 4) ? acc0[i & 3] : (i < 8) ? acc1[i & 3]
                           : (i < 12) ? acc2[i & 3] : acc3[i & 3];
            const float sq = fmaxf(fmaf(-2.0f, av, qs[i] + kq), 0.0f);
            const float t0 = __builtin_amdgcn_sqrtf(sq);     // t0 = dist
            const float u0 = fmaxf(fmaf(t0, COEF, KBIAS), 0.0f);
            l[i] += __uint_as_float((unsigned)u0);
        }
    }

    // sum l over the 16 column-lanes (butterfly within each quad's 16 lanes)
    #pragma unroll
    for (int s = 1; s < 16; s <<= 1) {
        #pragma unroll
        for (int i = 0; i < 16; ++i) l[i] += __shfl_xor(l[i], s);
    }

    if (l15 == 0) {
        #pragma unroll
        for (int i = 0; i < 16; ++i)
            atomicAdd(&part_l[rbase + (i >> 2) * 16 + quad * 4 + (i & 3)], l[i]);
    }

    __syncthreads();
    if (tid == 0) {
        __threadfence();
        s_last = (atomicAdd(&cnt[rb], 1u) == NCHUNK - 1) ? 1 : 0;
    }
    __syncthreads();
    if (s_last) {
        // all 16 chunk-blocks of this row-block done: finalize 256 rows
        const int row = rb * ROWBLK + tid;
        const float lf = atomicAdd(&part_l[row], 0.0f);          // coherent read
        float v = MEXP + __builtin_amdgcn_logf(lf) - diag2[row]; // log2 domain
        #pragma unroll
        for (int s = 1; s < 64; s <<= 1) v += __shfl_xor(v, s);
        if (lane == 0) red[wave] = v;
        __syncthreads();
        if (tid == 0)
            atomicAdd(out, (red[0] + red[1] + red[2] + red[3]) * (LN2 / (float)PP));
    }
}

// ---------------------------------------------------------------------------
extern "C" void kernel_launch(void* const* d_in, const int* in_sizes, int n_in,
                              void* d_out, int out_size, void* d_ws, size_t ws_size,
                              hipStream_t stream)
{
    const float* f1  = (const float*)d_in[0];   // [20000,256] f32
    const float* f2  = (const float*)d_in[1];   // [8192,256] f32
    const int*   map = (const int*)d_in[2];     // [8192] int
    float* out = (float*)d_out;

    // workspace layout (~8.1 MB)
    char* ws = (char*)d_ws;
    bf16_t*   qb2    = (bf16_t*)ws;                            // 512 grp * 8 KB = 4 MB
    bf16_t*   kb2    = qb2 + (size_t)512 * GS16;               // 4 MB + 8 KB slack
    float*    qsq    = (float*)(ws + (2ull * 512 * GS16 + 4096) * sizeof(bf16_t));
    float*    ksq    = qsq + PP;
    float*    diag2  = ksq + PP;
    float*    part_l = diag2 + PP;
    unsigned* cnt    = (unsigned*)(part_l + PP);

    nce_prep<<<PP / 4, 256, 0, stream>>>(f1, f2, map, qb2, kb2, qsq, ksq,
                                         diag2, part_l, cnt, out);
    nce_main<<<dim3(NROWBLK, NCHUNK), 256, 0, stream>>>(qb2, kb2, qsq, ksq,
                                                        diag2, part_l, cnt, out);
}